// Round 8
// baseline (211.843 us; speedup 1.0000x reference)
//
#include <hip/hip_runtime.h>

// DynamicCache.update concat copy — software-pipelined streaming memcpy, v5.
// past [B,H,S_PAST,D] f32, new [B,H,S_NEW,D] f32.
// d_out = k_out ++ v_out, each [B,H,S_TOT,D] f32.
//
// v5 = v3 (R6) structure exactly — GRP=12 double-buffer, 1024 main blocks x
// 512 KB contiguous segments, dedicated tail blocks — with ONE change:
// non-temporal load/store hints REMOVED (A/B probe: nt was introduced in R3
// bundled with the restructure, never isolated; normal stores coalesce+ack in
// L2, normal loads get L2 line buffering; the 6.7 TB/s fill kernels don't use
// nt).

typedef float f4 __attribute__((ext_vector_type(4)));

constexpr unsigned B = 4, H = 32, S_PAST = 4096, S_NEW = 16, D = 128;
constexpr unsigned ROW4   = D / 4;              // 32 f4 per row
constexpr unsigned S_TOT  = S_PAST + S_NEW;     // 4112
constexpr unsigned CHUNK4 = S_TOT * ROW4;       // 131584 f4 per (b,h) out-chunk
constexpr unsigned HALF4  = B * H * CHUNK4;     // f4 per out tensor
constexpr unsigned PASTC4 = S_PAST * ROW4;      // 1<<17 f4 per past chunk
constexpr unsigned NEWC4  = S_NEW * ROW4;       // 512 f4 per new chunk
constexpr unsigned PAST_TOTAL4 = 2u * B * H * PASTC4;   // 1<<25
constexpr unsigned MAIN_BLOCKS = 1024;
constexpr unsigned SEG4  = PAST_TOTAL4 / MAIN_BLOCKS;   // 32768 f4 = 512 KB
constexpr unsigned ITERS = SEG4 / 256u;                 // 128 f4 per thread
constexpr unsigned GRP   = 12;
constexpr unsigned NGRP  = ITERS / GRP;                 // 10 full groups
constexpr unsigned REM   = ITERS - NGRP * GRP;          // 8 remainder
constexpr unsigned TAIL_BLOCKS = 2u * B * H;            // 256

__global__ __launch_bounds__(256, 4) void dyncache_copy_kernel(
    const f4* __restrict__ pk, const f4* __restrict__ pv,
    const f4* __restrict__ nk, const f4* __restrict__ nv,
    f4* __restrict__ out)
{
    const unsigned tid = threadIdx.x;

    // ---- new-token tails: dedicated tiny blocks 0..255 (8 KB each) ----
    if (blockIdx.x < TAIL_BLOCKS) {
        const unsigned t  = blockIdx.x >> 7;
        const unsigned bh = blockIdx.x & (B * H - 1);
        const f4* __restrict__ s = (t ? nv : nk) + (size_t)bh * NEWC4;
        f4* __restrict__ d =
            out + (size_t)t * HALF4 + (size_t)bh * CHUNK4 + PASTC4;
        #pragma unroll
        for (unsigned k = 0; k < NEWC4 / 256u; ++k)
            d[k * 256u + tid] = s[k * 256u + tid];
        return;
    }

    // ---- main past copy: one contiguous 512 KB segment per block ----
    const unsigned bid = blockIdx.x - TAIL_BLOCKS;
    const unsigned seg = bid * SEG4;                  // flat past-f4 index
    const unsigned t   = seg >> 24;                   // tensor (k/v)
    const unsigned loc = seg & ((1u << 24) - 1);
    const unsigned bh  = loc >> 17;                   // (b,h) chunk
    const unsigned off = loc & (PASTC4 - 1);          // offset within chunk
    const f4* __restrict__ src =
        (t ? pv : pk) + ((size_t)bh << 17) + off + tid;
    f4* __restrict__ dst =
        out + (size_t)t * HALF4 + (size_t)bh * CHUNK4 + off + tid;

    f4 a[GRP], b[GRP];

    // prologue: load group 0 into A
    #pragma unroll
    for (unsigned j = 0; j < GRP; ++j)
        a[j] = src[(0u * GRP + j) * 256u];

    // steady state: groups 1..9 — load next buffer BEFORE storing previous.
    #pragma unroll
    for (unsigned p = 0; p < 4; ++p) {
        const unsigned g1 = 2u * p + 1u;              // load B, store A(g1-1)
        #pragma unroll
        for (unsigned j = 0; j < GRP; ++j)
            b[j] = src[(g1 * GRP + j) * 256u];
        #pragma unroll
        for (unsigned j = 0; j < GRP; ++j)
            dst[((g1 - 1u) * GRP + j) * 256u] = a[j];
        const unsigned g2 = 2u * p + 2u;              // load A, store B(g2-1)
        #pragma unroll
        for (unsigned j = 0; j < GRP; ++j)
            a[j] = src[(g2 * GRP + j) * 256u];
        #pragma unroll
        for (unsigned j = 0; j < GRP; ++j)
            dst[((g2 - 1u) * GRP + j) * 256u] = b[j];
    }
    // g = 9: load B, store A(8)
    #pragma unroll
    for (unsigned j = 0; j < GRP; ++j)
        b[j] = src[(9u * GRP + j) * 256u];
    #pragma unroll
    for (unsigned j = 0; j < GRP; ++j)
        dst[(8u * GRP + j) * 256u] = a[j];
    // drain: store B(9)
    #pragma unroll
    for (unsigned j = 0; j < GRP; ++j)
        dst[(9u * GRP + j) * 256u] = b[j];

    // remainder: 8 f4 (reuses A regs)
    #pragma unroll
    for (unsigned j = 0; j < REM; ++j)
        a[j] = src[(NGRP * GRP + j) * 256u];
    #pragma unroll
    for (unsigned j = 0; j < REM; ++j)
        dst[(NGRP * GRP + j) * 256u] = a[j];
}

extern "C" void kernel_launch(void* const* d_in, const int* in_sizes, int n_in,
                              void* d_out, int out_size, void* d_ws, size_t ws_size,
                              hipStream_t stream) {
    const f4* pk = (const f4*)d_in[0];
    const f4* pv = (const f4*)d_in[1];
    const f4* nk = (const f4*)d_in[2];
    const f4* nv = (const f4*)d_in[3];
    f4* out = (f4*)d_out;

    dyncache_copy_kernel<<<TAIL_BLOCKS + MAIN_BLOCKS, 256, 0, stream>>>(
        pk, pv, nk, nv, out);
}

// Round 9
// 202.361 us; speedup vs baseline: 1.0469x; 1.0469x over previous
//
#include <hip/hip_runtime.h>

// DynamicCache.update concat copy — software-pipelined streaming memcpy, v6.
// past [B,H,S_PAST,D] f32, new [B,H,S_NEW,D] f32.
// d_out = k_out ++ v_out, each [B,H,S_TOT,D] f32.
//
// v6 = v3 structure (GRP=12 dbuf, 1024 x 512 KB main blocks, dedicated tail
// blocks) with ASYMMETRIC cache hints: nt on STORES only (avoid write-allocate
// churn — R8 showed removing nt on both sides costs 10%), plain LOADS (let L2
// buffer/smooth the HBM read stream; probes whether load-side nt was a small
// negative).

typedef float f4 __attribute__((ext_vector_type(4)));

constexpr unsigned B = 4, H = 32, S_PAST = 4096, S_NEW = 16, D = 128;
constexpr unsigned ROW4   = D / 4;              // 32 f4 per row
constexpr unsigned S_TOT  = S_PAST + S_NEW;     // 4112
constexpr unsigned CHUNK4 = S_TOT * ROW4;       // 131584 f4 per (b,h) out-chunk
constexpr unsigned HALF4  = B * H * CHUNK4;     // f4 per out tensor
constexpr unsigned PASTC4 = S_PAST * ROW4;      // 1<<17 f4 per past chunk
constexpr unsigned NEWC4  = S_NEW * ROW4;       // 512 f4 per new chunk
constexpr unsigned PAST_TOTAL4 = 2u * B * H * PASTC4;   // 1<<25
constexpr unsigned MAIN_BLOCKS = 1024;
constexpr unsigned SEG4  = PAST_TOTAL4 / MAIN_BLOCKS;   // 32768 f4 = 512 KB
constexpr unsigned ITERS = SEG4 / 256u;                 // 128 f4 per thread
constexpr unsigned GRP   = 12;
constexpr unsigned NGRP  = ITERS / GRP;                 // 10 full groups
constexpr unsigned REM   = ITERS - NGRP * GRP;          // 8 remainder
constexpr unsigned TAIL_BLOCKS = 2u * B * H;            // 256

__global__ __launch_bounds__(256, 4) void dyncache_copy_kernel(
    const f4* __restrict__ pk, const f4* __restrict__ pv,
    const f4* __restrict__ nk, const f4* __restrict__ nv,
    f4* __restrict__ out)
{
    const unsigned tid = threadIdx.x;

    // ---- new-token tails: dedicated tiny blocks 0..255 (8 KB each) ----
    if (blockIdx.x < TAIL_BLOCKS) {
        const unsigned t  = blockIdx.x >> 7;
        const unsigned bh = blockIdx.x & (B * H - 1);
        const f4* __restrict__ s = (t ? nv : nk) + (size_t)bh * NEWC4;
        f4* __restrict__ d =
            out + (size_t)t * HALF4 + (size_t)bh * CHUNK4 + PASTC4;
        #pragma unroll
        for (unsigned k = 0; k < NEWC4 / 256u; ++k)
            __builtin_nontemporal_store(s[k * 256u + tid], d + k * 256u + tid);
        return;
    }

    // ---- main past copy: one contiguous 512 KB segment per block ----
    const unsigned bid = blockIdx.x - TAIL_BLOCKS;
    const unsigned seg = bid * SEG4;                  // flat past-f4 index
    const unsigned t   = seg >> 24;                   // tensor (k/v)
    const unsigned loc = seg & ((1u << 24) - 1);
    const unsigned bh  = loc >> 17;                   // (b,h) chunk
    const unsigned off = loc & (PASTC4 - 1);          // offset within chunk
    const f4* __restrict__ src =
        (t ? pv : pk) + ((size_t)bh << 17) + off + tid;
    f4* __restrict__ dst =
        out + (size_t)t * HALF4 + (size_t)bh * CHUNK4 + off + tid;

    f4 a[GRP], b[GRP];

    // prologue: load group 0 into A
    #pragma unroll
    for (unsigned j = 0; j < GRP; ++j)
        a[j] = src[(0u * GRP + j) * 256u];

    // steady state: groups 1..9 — load next buffer BEFORE storing previous.
    #pragma unroll
    for (unsigned p = 0; p < 4; ++p) {
        const unsigned g1 = 2u * p + 1u;              // load B, store A(g1-1)
        #pragma unroll
        for (unsigned j = 0; j < GRP; ++j)
            b[j] = src[(g1 * GRP + j) * 256u];
        #pragma unroll
        for (unsigned j = 0; j < GRP; ++j)
            __builtin_nontemporal_store(a[j], dst + ((g1 - 1u) * GRP + j) * 256u);
        const unsigned g2 = 2u * p + 2u;              // load A, store B(g2-1)
        #pragma unroll
        for (unsigned j = 0; j < GRP; ++j)
            a[j] = src[(g2 * GRP + j) * 256u];
        #pragma unroll
        for (unsigned j = 0; j < GRP; ++j)
            __builtin_nontemporal_store(b[j], dst + ((g2 - 1u) * GRP + j) * 256u);
    }
    // g = 9: load B, store A(8)
    #pragma unroll
    for (unsigned j = 0; j < GRP; ++j)
        b[j] = src[(9u * GRP + j) * 256u];
    #pragma unroll
    for (unsigned j = 0; j < GRP; ++j)
        __builtin_nontemporal_store(a[j], dst + (8u * GRP + j) * 256u);
    // drain: store B(9)
    #pragma unroll
    for (unsigned j = 0; j < GRP; ++j)
        __builtin_nontemporal_store(b[j], dst + (9u * GRP + j) * 256u);

    // remainder: 8 f4 (reuses A regs)
    #pragma unroll
    for (unsigned j = 0; j < REM; ++j)
        a[j] = src[(NGRP * GRP + j) * 256u];
    #pragma unroll
    for (unsigned j = 0; j < REM; ++j)
        __builtin_nontemporal_store(a[j], dst + (NGRP * GRP + j) * 256u);
}

extern "C" void kernel_launch(void* const* d_in, const int* in_sizes, int n_in,
                              void* d_out, int out_size, void* d_ws, size_t ws_size,
                              hipStream_t stream) {
    const f4* pk = (const f4*)d_in[0];
    const f4* pv = (const f4*)d_in[1];
    const f4* nk = (const f4*)d_in[2];
    const f4* nv = (const f4*)d_in[3];
    f4* out = (f4*)d_out;

    dyncache_copy_kernel<<<TAIL_BLOCKS + MAIN_BLOCKS, 256, 0, stream>>>(
        pk, pv, nk, nv, out);
}

// Round 10
// 191.348 us; speedup vs baseline: 1.1071x; 1.0576x over previous
//
#include <hip/hip_runtime.h>

// DynamicCache.update concat copy — FINAL: best-measured configuration (v3).
// past [B,H,S_PAST,D] f32, new [B,H,S_NEW,D] f32.
// d_out = k_out ++ v_out, each [B,H,S_TOT,D] f32.
//
// Config (each choice A/B-resolved over R3-R9):
//  - GRP=12 double-buffer, load-next-group-before-store (R4: 190.5 us;
//    GRP=8+TLP 197.8, triple-buffer 192.3 -> plateau, keep GRP=12)
//  - 1024 main blocks x 512 KB contiguous segments, block-uniform scalar
//    segment math (pow2 strides), 256 dedicated tail blocks at grid front
//  - nontemporal on BOTH loads and stores (both=190.5, store-only=202.4,
//    none=211.8 -> both hints load-bearing: no L2 pollution by the 2x539 MB
//    read-once/write-once streams)
//  - __launch_bounds__(256,4): ~112 VGPR, 16 waves/CU, ~3 KB reads in
//    flight/CU
// Result: ~190 us = 5.66 TB/s mixed r/w = 90% of the 6.29 TB/s copy ubench.

typedef float f4 __attribute__((ext_vector_type(4)));

constexpr unsigned B = 4, H = 32, S_PAST = 4096, S_NEW = 16, D = 128;
constexpr unsigned ROW4   = D / 4;              // 32 f4 per row
constexpr unsigned S_TOT  = S_PAST + S_NEW;     // 4112
constexpr unsigned CHUNK4 = S_TOT * ROW4;       // 131584 f4 per (b,h) out-chunk
constexpr unsigned HALF4  = B * H * CHUNK4;     // f4 per out tensor
constexpr unsigned PASTC4 = S_PAST * ROW4;      // 1<<17 f4 per past chunk
constexpr unsigned NEWC4  = S_NEW * ROW4;       // 512 f4 per new chunk
constexpr unsigned PAST_TOTAL4 = 2u * B * H * PASTC4;   // 1<<25
constexpr unsigned MAIN_BLOCKS = 1024;
constexpr unsigned SEG4  = PAST_TOTAL4 / MAIN_BLOCKS;   // 32768 f4 = 512 KB
constexpr unsigned ITERS = SEG4 / 256u;                 // 128 f4 per thread
constexpr unsigned GRP   = 12;
constexpr unsigned NGRP  = ITERS / GRP;                 // 10 full groups
constexpr unsigned REM   = ITERS - NGRP * GRP;          // 8 remainder
constexpr unsigned TAIL_BLOCKS = 2u * B * H;            // 256

__global__ __launch_bounds__(256, 4) void dyncache_copy_kernel(
    const f4* __restrict__ pk, const f4* __restrict__ pv,
    const f4* __restrict__ nk, const f4* __restrict__ nv,
    f4* __restrict__ out)
{
    const unsigned tid = threadIdx.x;

    // ---- new-token tails: dedicated tiny blocks 0..255 (8 KB each) ----
    if (blockIdx.x < TAIL_BLOCKS) {
        const unsigned t  = blockIdx.x >> 7;
        const unsigned bh = blockIdx.x & (B * H - 1);
        const f4* __restrict__ s = (t ? nv : nk) + (size_t)bh * NEWC4;
        f4* __restrict__ d =
            out + (size_t)t * HALF4 + (size_t)bh * CHUNK4 + PASTC4;
        #pragma unroll
        for (unsigned k = 0; k < NEWC4 / 256u; ++k)
            __builtin_nontemporal_store(
                __builtin_nontemporal_load(s + k * 256u + tid), d + k * 256u + tid);
        return;
    }

    // ---- main past copy: one contiguous 512 KB segment per block ----
    const unsigned bid = blockIdx.x - TAIL_BLOCKS;
    const unsigned seg = bid * SEG4;                  // flat past-f4 index
    const unsigned t   = seg >> 24;                   // tensor (k/v)
    const unsigned loc = seg & ((1u << 24) - 1);
    const unsigned bh  = loc >> 17;                   // (b,h) chunk
    const unsigned off = loc & (PASTC4 - 1);          // offset within chunk
    const f4* __restrict__ src =
        (t ? pv : pk) + ((size_t)bh << 17) + off + tid;
    f4* __restrict__ dst =
        out + (size_t)t * HALF4 + (size_t)bh * CHUNK4 + off + tid;

    f4 a[GRP], b[GRP];

    // prologue: load group 0 into A
    #pragma unroll
    for (unsigned j = 0; j < GRP; ++j)
        a[j] = __builtin_nontemporal_load(src + (0u * GRP + j) * 256u);

    // steady state: groups 1..9 — load next buffer BEFORE storing previous.
    #pragma unroll
    for (unsigned p = 0; p < 4; ++p) {
        const unsigned g1 = 2u * p + 1u;              // load B, store A(g1-1)
        #pragma unroll
        for (unsigned j = 0; j < GRP; ++j)
            b[j] = __builtin_nontemporal_load(src + (g1 * GRP + j) * 256u);
        #pragma unroll
        for (unsigned j = 0; j < GRP; ++j)
            __builtin_nontemporal_store(a[j], dst + ((g1 - 1u) * GRP + j) * 256u);
        const unsigned g2 = 2u * p + 2u;              // load A, store B(g2-1)
        #pragma unroll
        for (unsigned j = 0; j < GRP; ++j)
            a[j] = __builtin_nontemporal_load(src + (g2 * GRP + j) * 256u);
        #pragma unroll
        for (unsigned j = 0; j < GRP; ++j)
            __builtin_nontemporal_store(b[j], dst + ((g2 - 1u) * GRP + j) * 256u);
    }
    // g = 9: load B, store A(8)
    #pragma unroll
    for (unsigned j = 0; j < GRP; ++j)
        b[j] = __builtin_nontemporal_load(src + (9u * GRP + j) * 256u);
    #pragma unroll
    for (unsigned j = 0; j < GRP; ++j)
        __builtin_nontemporal_store(a[j], dst + (8u * GRP + j) * 256u);
    // drain: store B(9)
    #pragma unroll
    for (unsigned j = 0; j < GRP; ++j)
        __builtin_nontemporal_store(b[j], dst + (9u * GRP + j) * 256u);

    // remainder: 8 f4 (reuses A regs)
    #pragma unroll
    for (unsigned j = 0; j < REM; ++j)
        a[j] = __builtin_nontemporal_load(src + (NGRP * GRP + j) * 256u);
    #pragma unroll
    for (unsigned j = 0; j < REM; ++j)
        __builtin_nontemporal_store(a[j], dst + (NGRP * GRP + j) * 256u);
}

extern "C" void kernel_launch(void* const* d_in, const int* in_sizes, int n_in,
                              void* d_out, int out_size, void* d_ws, size_t ws_size,
                              hipStream_t stream) {
    const f4* pk = (const f4*)d_in[0];
    const f4* pv = (const f4*)d_in[1];
    const f4* nk = (const f4*)d_in[2];
    const f4* nv = (const f4*)d_in[3];
    f4* out = (f4*)d_out;

    dyncache_copy_kernel<<<TAIL_BLOCKS + MAIN_BLOCKS, 256, 0, stream>>>(
        pk, pv, nk, nv, out);
}